// Round 1
// baseline (1791.287 us; speedup 1.0000x reference)
//
#include <hip/hip_runtime.h>

constexpr int C_DIM = 256;

// ---------------- CSR build ----------------

__global__ void k_zero_i32(int* __restrict__ p, int n) {
    int i = blockIdx.x * blockDim.x + threadIdx.x;
    if (i < n) p[i] = 0;
}

__global__ void k_hist(const int* __restrict__ dst, int E, int* __restrict__ cnt) {
    int e = blockIdx.x * blockDim.x + threadIdx.x;
    if (e < E) atomicAdd(&cnt[dst[e]], 1);
}

// one-block exclusive scan: off[0..n-1] = exclusive prefix of cnt, off[n] = total
__global__ __launch_bounds__(1024) void k_scan(const int* __restrict__ cnt,
                                               int* __restrict__ off, int n) {
    __shared__ int sh[1024];
    const int tid = threadIdx.x;
    const int chunk = (n + 1023) >> 10;
    const int s = tid * chunk;
    const int e = min(s + chunk, n);
    int sum = 0;
    for (int i = s; i < e; i++) sum += cnt[i];
    sh[tid] = sum;
    __syncthreads();
    for (int ofs = 1; ofs < 1024; ofs <<= 1) {
        int t = (tid >= ofs) ? sh[tid - ofs] : 0;
        __syncthreads();
        sh[tid] += t;
        __syncthreads();
    }
    int run = sh[tid] - sum;   // exclusive prefix for this chunk
    for (int i = s; i < e; i++) { off[i] = run; run += cnt[i]; }
    if (tid == 1023) off[n] = sh[1023];
}

__global__ void k_copy_i32(const int* __restrict__ a, int* __restrict__ b, int n) {
    int i = blockIdx.x * blockDim.x + threadIdx.x;
    if (i < n) b[i] = a[i];
}

__global__ void k_scatter(const int* __restrict__ src, const int* __restrict__ dst, int E,
                          int* __restrict__ cur, int* __restrict__ adj) {
    int e = blockIdx.x * blockDim.x + threadIdx.x;
    if (e < E) {
        int p = atomicAdd(&cur[dst[e]], 1);
        adj[p] = src[e];
    }
}

// ---------------- H = x + A*x (GIN agg, eps=0) ----------------
// 256 threads = 4 waves; one wave per node; lane handles 4 channels (float4).
__global__ __launch_bounds__(256) void k_agg(const float* __restrict__ x,
                                             const int* __restrict__ off,
                                             const int* __restrict__ adj,
                                             float* __restrict__ H, int n) {
    const int node = blockIdx.x * 4 + (threadIdx.x >> 6);
    if (node >= n) return;
    const int lane = threadIdx.x & 63;
    float4 acc = ((const float4*)(x + (size_t)node * C_DIM))[lane];
    const int s = off[node], e = off[node + 1];
    for (int j = s; j < e; j++) {
        const int sn = adj[j];
        float4 v = ((const float4*)(x + (size_t)sn * C_DIM))[lane];
        acc.x += v.x; acc.y += v.y; acc.z += v.z; acc.w += v.w;
    }
    ((float4*)(H + (size_t)node * C_DIM))[lane] = acc;
}

// ---------------- Y = act(X @ W + b) fp32 vector GEMM ----------------
// X:[n,K] row-major, W:[K,M] row-major, b:[M]. BM=BN=64, BK=32,
// 256 threads as 16x16, 4x4 microtile. X tile stored K-major in LDS so both
// operand reads are ds_read_b128.
template <int RELU>
__global__ __launch_bounds__(256) void k_gemm(const float* __restrict__ X,
                                              const float* __restrict__ W,
                                              const float* __restrict__ bias,
                                              float* __restrict__ Y,
                                              int n, int K, int M) {
    __shared__ float Xst[32][68];  // [kk][row], +4 pad keeps 16B alignment, spreads banks
    __shared__ float Ws[32][64];   // [kk][col]
    const int tid = threadIdx.x;
    const int tx = tid & 15, ty = tid >> 4;
    const int row0 = blockIdx.x * 64, col0 = blockIdx.y * 64;
    float acc[4][4] = {};

    for (int k0 = 0; k0 < K; k0 += 32) {
        __syncthreads();
        // X tile: 64 rows x 32 cols -> transposed into Xst[kk][row]
        for (int q = tid; q < 512; q += 256) {
            const int r = q >> 3, c4 = q & 7;
            const int row = row0 + r;
            float4 v = make_float4(0.f, 0.f, 0.f, 0.f);
            if (row < n) v = *(const float4*)(X + (size_t)row * K + (k0 + c4 * 4));
            Xst[c4 * 4 + 0][r] = v.x;
            Xst[c4 * 4 + 1][r] = v.y;
            Xst[c4 * 4 + 2][r] = v.z;
            Xst[c4 * 4 + 3][r] = v.w;
        }
        // W tile: 32 rows x 64 cols
        for (int q = tid; q < 512; q += 256) {
            const int kk = q >> 4, c4 = q & 15;
            *(float4*)&Ws[kk][c4 * 4] =
                *(const float4*)(W + (size_t)(k0 + kk) * M + (col0 + c4 * 4));
        }
        __syncthreads();
#pragma unroll
        for (int kk = 0; kk < 32; kk++) {
            const float4 a = *(const float4*)&Xst[kk][ty * 4];
            const float4 b = *(const float4*)&Ws[kk][tx * 4];
            const float a_[4] = {a.x, a.y, a.z, a.w};
            const float b_[4] = {b.x, b.y, b.z, b.w};
#pragma unroll
            for (int i = 0; i < 4; i++)
#pragma unroll
                for (int j = 0; j < 4; j++)
                    acc[i][j] = fmaf(a_[i], b_[j], acc[i][j]);
        }
    }

    const float4 bv = *(const float4*)(bias + col0 + tx * 4);
#pragma unroll
    for (int i = 0; i < 4; i++) {
        const int row = row0 + ty * 4 + i;
        if (row < n) {
            float4 o;
            o.x = acc[i][0] + bv.x;
            o.y = acc[i][1] + bv.y;
            o.z = acc[i][2] + bv.z;
            o.w = acc[i][3] + bv.w;
            if (RELU) {
                o.x = fmaxf(o.x, 0.f); o.y = fmaxf(o.y, 0.f);
                o.z = fmaxf(o.z, 0.f); o.w = fmaxf(o.w, 0.f);
            }
            *(float4*)(Y + (size_t)row * M + (col0 + tx * 4)) = o;
        }
    }
}

// ---------------- driver ----------------

extern "C" void kernel_launch(void* const* d_in, const int* in_sizes, int n_in,
                              void* d_out, int out_size, void* d_ws, size_t ws_size,
                              hipStream_t stream) {
    const float* x   = (const float*)d_in[0];
    const int*   src = (const int*)d_in[1];
    const int*   dst = (const int*)d_in[2];
    const float* W1s = (const float*)d_in[3];
    const float* b1s = (const float*)d_in[4];
    const float* W2s = (const float*)d_in[5];
    const float* b2s = (const float*)d_in[6];
    const float* W3s = (const float*)d_in[7];
    const float* b3s = (const float*)d_in[8];
    const float* cW1 = (const float*)d_in[9];
    const float* cb1 = (const float*)d_in[10];
    const float* cW2 = (const float*)d_in[11];
    const float* cb2 = (const float*)d_in[12];
    const float* cW3 = (const float*)d_in[13];
    const float* cb3 = (const float*)d_in[14];

    const int n  = in_sizes[0] / C_DIM;                 // 50000
    const int E  = in_sizes[1];                         // 800000
    const int NL = in_sizes[3] / (C_DIM * C_DIM);       // 3 inner layers

    char* w = (char*)d_ws;
    size_t o = 0;
    auto take = [&](size_t bytes) -> char* {
        char* p = w + o;
        o = (o + bytes + 255) & ~(size_t)255;
        return p;
    };
    int*   off  = (int*)take(sizeof(int) * (size_t)(n + 1));
    int*   cur  = (int*)take(sizeof(int) * (size_t)n);
    int*   adj  = (int*)take(sizeof(int) * (size_t)E);
    float* bufH = (float*)take(sizeof(float) * (size_t)n * C_DIM);
    float* bufA = (float*)take(sizeof(float) * (size_t)n * C_DIM);
    float* out  = (float*)d_out;  // doubles as third activation buffer

    const dim3 b256(256);
    // CSR build (counts in cur, then cur becomes the scatter cursor)
    k_zero_i32<<<dim3((n + 255) / 256), b256, 0, stream>>>(cur, n);
    k_hist<<<dim3((E + 255) / 256), b256, 0, stream>>>(dst, E, cur);
    k_scan<<<1, 1024, 0, stream>>>(cur, off, n);
    k_copy_i32<<<dim3((n + 255) / 256), b256, 0, stream>>>(off, cur, n);
    k_scatter<<<dim3((E + 255) / 256), b256, 0, stream>>>(src, dst, E, cur, adj);

    const int gx = (n + 63) / 64;
    const dim3 gAgg((n + 3) / 4);

    const float* xp = x;
    for (int l = 0; l < NL; l++) {
        const size_t wo = (size_t)l * C_DIM * C_DIM;
        k_agg<<<gAgg, b256, 0, stream>>>(xp, off, adj, bufH, n);
        k_gemm<1><<<dim3(gx, 4), b256, 0, stream>>>(bufH, W1s + wo, b1s + l * C_DIM, bufA, n, 256, 256);
        k_gemm<1><<<dim3(gx, 4), b256, 0, stream>>>(bufA, W2s + wo, b2s + l * C_DIM, out,  n, 256, 256);
        k_gemm<0><<<dim3(gx, 4), b256, 0, stream>>>(out,  W3s + wo, b3s + l * C_DIM, bufA, n, 256, 256);
        xp = bufA;
    }
    // final conv: C->C (relu), C->64 (relu), 64->C (linear)
    k_agg<<<gAgg, b256, 0, stream>>>(xp, off, adj, bufH, n);
    k_gemm<1><<<dim3(gx, 4), b256, 0, stream>>>(bufH, cW1, cb1, bufA, n, 256, 256);
    k_gemm<1><<<dim3(gx, 1), b256, 0, stream>>>(bufA, cW2, cb2, bufH, n, 256, 64);
    k_gemm<0><<<dim3(gx, 4), b256, 0, stream>>>(bufH, cW3, cb3, out, n, 64, 256);
}

// Round 3
// 1248.406 us; speedup vs baseline: 1.4349x; 1.4349x over previous
//
#include <hip/hip_runtime.h>

constexpr int C_DIM = 256;

using f32x4  = __attribute__((ext_vector_type(4))) float;
using bf16x8 = __attribute__((ext_vector_type(8))) short;

// ---------------- CSR build ----------------

__global__ void k_zero_i32(int* __restrict__ p, int n) {
    int i = blockIdx.x * blockDim.x + threadIdx.x;
    if (i < n) p[i] = 0;
}

__global__ void k_hist(const int* __restrict__ dst, int E, int* __restrict__ cnt) {
    int e = blockIdx.x * blockDim.x + threadIdx.x;
    if (e < E) atomicAdd(&cnt[dst[e]], 1);
}

__global__ __launch_bounds__(1024) void k_scan(const int* __restrict__ cnt,
                                               int* __restrict__ off, int n) {
    __shared__ int sh[1024];
    const int tid = threadIdx.x;
    const int chunk = (n + 1023) >> 10;
    const int s = tid * chunk;
    const int e = min(s + chunk, n);
    int sum = 0;
    for (int i = s; i < e; i++) sum += cnt[i];
    sh[tid] = sum;
    __syncthreads();
    for (int ofs = 1; ofs < 1024; ofs <<= 1) {
        int t = (tid >= ofs) ? sh[tid - ofs] : 0;
        __syncthreads();
        sh[tid] += t;
        __syncthreads();
    }
    int run = sh[tid] - sum;
    for (int i = s; i < e; i++) { off[i] = run; run += cnt[i]; }
    if (tid == 1023) off[n] = sh[1023];
}

__global__ void k_copy_i32(const int* __restrict__ a, int* __restrict__ b, int n) {
    int i = blockIdx.x * blockDim.x + threadIdx.x;
    if (i < n) b[i] = a[i];
}

__global__ void k_scatter(const int* __restrict__ src, const int* __restrict__ dst, int E,
                          int* __restrict__ cur, int* __restrict__ adj) {
    int e = blockIdx.x * blockDim.x + threadIdx.x;
    if (e < E) {
        int p = atomicAdd(&cur[dst[e]], 1);
        adj[p] = src[e];
    }
}

// ---------------- H = x + A*x ----------------
__global__ __launch_bounds__(256) void k_agg(const float* __restrict__ x,
                                             const int* __restrict__ off,
                                             const int* __restrict__ adj,
                                             float* __restrict__ H, int n) {
    const int node = blockIdx.x * 4 + (threadIdx.x >> 6);
    if (node >= n) return;
    const int lane = threadIdx.x & 63;
    float4 acc = ((const float4*)(x + (size_t)node * C_DIM))[lane];
    const int s = off[node], e = off[node + 1];
    for (int j = s; j < e; j++) {
        const int sn = adj[j];
        float4 v = ((const float4*)(x + (size_t)sn * C_DIM))[lane];
        acc.x += v.x; acc.y += v.y; acc.z += v.z; acc.w += v.w;
    }
    ((float4*)(H + (size_t)node * C_DIM))[lane] = acc;
}

// ---------------- weight split + transpose ----------------
// W: count stacked [K][M] fp32 -> Wt_hi/lo: count stacked [M][K] bf16 (truncation split)
__global__ void k_split_w(const float* __restrict__ W, ushort* __restrict__ hi,
                          ushort* __restrict__ lo, int K, int M, int total) {
    int i = blockIdx.x * blockDim.x + threadIdx.x;
    if (i >= total) return;
    const int KM = K * M;
    const int mi = i / KM, rem = i - mi * KM;
    const int k = rem / M, m = rem - k * M;
    const float x = W[i];
    const uint u = __float_as_uint(x);
    const float hf = __uint_as_float(u & 0xffff0000u);
    const float lf = x - hf;
    const int oidx = mi * KM + m * K + k;
    hi[oidx] = (ushort)(u >> 16);
    lo[oidx] = (ushort)(__float_as_uint(lf) >> 16);
}

// ---------------- Y = act(X @ W + b), MFMA split-bf16 ----------------
// X:[n,K] fp32 row-major. WtH/WtL:[M][K] bf16 (pre-transposed). Y:[n,M] fp32.
// 64x64 tile, BK=32, 4 waves each owning a 32x32 quadrant (2x2 fragments of 16x16x32).
template <int RELU>
__global__ __launch_bounds__(256) void k_gemm_mfma(const float* __restrict__ X,
        const ushort* __restrict__ WtH, const ushort* __restrict__ WtL,
        const float* __restrict__ bias, float* __restrict__ Y,
        int n, int K, int M) {
    __shared__ ushort AsH[64][40], AsL[64][40], BsH[64][40], BsL[64][40];
    const int tid = threadIdx.x;
    const int l = tid & 63, w = tid >> 6;
    const int wr = w >> 1, wc = w & 1;
    const int lr = l & 15, lkq = l >> 4;        // k-quadrant 0..3
    const int lk = lkq * 8;
    const int row0 = blockIdx.x * 64, col0 = blockIdx.y * 64;
    f32x4 acc[2][2] = {};

    const int ar = tid >> 3, ac4 = tid & 7;     // A staging coords
    const int bcol = tid >> 2, bq = tid & 3;    // B staging coords

    for (int k0 = 0; k0 < K; k0 += 32) {
        __syncthreads();
        // stage A: 64 rows x 32 k, fp32 -> bf16 hi/lo
#pragma unroll
        for (int h = 0; h < 2; h++) {
            const int r = ar + h * 32;
            const int row = row0 + r;
            float4 v = make_float4(0.f, 0.f, 0.f, 0.f);
            if (row < n) v = *(const float4*)(X + (size_t)row * K + k0 + ac4 * 4);
            const uint u0 = __float_as_uint(v.x), u1 = __float_as_uint(v.y);
            const uint u2 = __float_as_uint(v.z), u3 = __float_as_uint(v.w);
            uint2 hv;
            hv.x = (u0 >> 16) | (u1 & 0xffff0000u);
            hv.y = (u2 >> 16) | (u3 & 0xffff0000u);
            const float l0 = v.x - __uint_as_float(u0 & 0xffff0000u);
            const float l1 = v.y - __uint_as_float(u1 & 0xffff0000u);
            const float l2 = v.z - __uint_as_float(u2 & 0xffff0000u);
            const float l3 = v.w - __uint_as_float(u3 & 0xffff0000u);
            uint2 lv;
            lv.x = (__float_as_uint(l0) >> 16) | (__float_as_uint(l1) & 0xffff0000u);
            lv.y = (__float_as_uint(l2) >> 16) | (__float_as_uint(l3) & 0xffff0000u);
            *(uint2*)&AsH[r][ac4 * 4] = hv;
            *(uint2*)&AsL[r][ac4 * 4] = lv;
        }
        // stage B: 64 cols x 32 k, already bf16 [col][k] in global
        {
            const size_t g = (size_t)(col0 + bcol) * K + k0 + bq * 8;
            *(uint4*)&BsH[bcol][bq * 8] = *(const uint4*)(WtH + g);
            *(uint4*)&BsL[bcol][bq * 8] = *(const uint4*)(WtL + g);
        }
        __syncthreads();

        bf16x8 aH[2], aL[2], bH[2], bL[2];
#pragma unroll
        for (int f = 0; f < 2; f++) {
            aH[f] = *(const bf16x8*)&AsH[wr * 32 + f * 16 + lr][lk];
            aL[f] = *(const bf16x8*)&AsL[wr * 32 + f * 16 + lr][lk];
            bH[f] = *(const bf16x8*)&BsH[wc * 32 + f * 16 + lr][lk];
            bL[f] = *(const bf16x8*)&BsL[wc * 32 + f * 16 + lr][lk];
        }
#pragma unroll
        for (int fi = 0; fi < 2; fi++)
#pragma unroll
            for (int fj = 0; fj < 2; fj++) {
                acc[fi][fj] = __builtin_amdgcn_mfma_f32_16x16x32_bf16(aH[fi], bH[fj], acc[fi][fj], 0, 0, 0);
                acc[fi][fj] = __builtin_amdgcn_mfma_f32_16x16x32_bf16(aL[fi], bH[fj], acc[fi][fj], 0, 0, 0);
                acc[fi][fj] = __builtin_amdgcn_mfma_f32_16x16x32_bf16(aH[fi], bL[fj], acc[fi][fj], 0, 0, 0);
            }
    }

    // epilogue: C/D layout col=lane&15, row=(lane>>4)*4+reg
#pragma unroll
    for (int fi = 0; fi < 2; fi++)
#pragma unroll
        for (int fj = 0; fj < 2; fj++) {
            const int col = col0 + wc * 32 + fj * 16 + lr;
            const float bv = bias[col];
#pragma unroll
            for (int r = 0; r < 4; r++) {
                const int row = row0 + wr * 32 + fi * 16 + lkq * 4 + r;
                if (row < n) {
                    float v = acc[fi][fj][r] + bv;
                    if (RELU) v = fmaxf(v, 0.f);
                    Y[(size_t)row * M + col] = v;
                }
            }
        }
}

// ---------------- driver ----------------

extern "C" void kernel_launch(void* const* d_in, const int* in_sizes, int n_in,
                              void* d_out, int out_size, void* d_ws, size_t ws_size,
                              hipStream_t stream) {
    const float* x   = (const float*)d_in[0];
    const int*   src = (const int*)d_in[1];
    const int*   dst = (const int*)d_in[2];
    const float* W1s = (const float*)d_in[3];
    const float* b1s = (const float*)d_in[4];
    const float* W2s = (const float*)d_in[5];
    const float* b2s = (const float*)d_in[6];
    const float* W3s = (const float*)d_in[7];
    const float* b3s = (const float*)d_in[8];
    const float* cW1 = (const float*)d_in[9];
    const float* cb1 = (const float*)d_in[10];
    const float* cW2 = (const float*)d_in[11];
    const float* cb2 = (const float*)d_in[12];
    const float* cW3 = (const float*)d_in[13];
    const float* cb3 = (const float*)d_in[14];

    const int n  = in_sizes[0] / C_DIM;                 // 50000
    const int E  = in_sizes[1];                         // 800000
    const int NL = in_sizes[3] / (C_DIM * C_DIM);       // 3 inner layers

    char* w = (char*)d_ws;
    size_t o = 0;
    auto take = [&](size_t bytes) -> char* {
        char* p = w + o;
        o = (o + bytes + 255) & ~(size_t)255;
        return p;
    };
    int*   off  = (int*)take(sizeof(int) * (size_t)(n + 1));
    int*   cur  = (int*)take(sizeof(int) * (size_t)n);
    int*   adj  = (int*)take(sizeof(int) * (size_t)E);
    float* bufH = (float*)take(sizeof(float) * (size_t)n * C_DIM);
    float* bufA = (float*)take(sizeof(float) * (size_t)n * C_DIM);
    const int szW  = NL * C_DIM * C_DIM;   // 3*65536
    const int szC1 = C_DIM * C_DIM;
    const int szC2 = C_DIM * 64;
    const int szC3 = 64 * C_DIM;
    ushort* W1tH = (ushort*)take(2ull * szW);
    ushort* W1tL = (ushort*)take(2ull * szW);
    ushort* W2tH = (ushort*)take(2ull * szW);
    ushort* W2tL = (ushort*)take(2ull * szW);
    ushort* W3tH = (ushort*)take(2ull * szW);
    ushort* W3tL = (ushort*)take(2ull * szW);
    ushort* C1tH = (ushort*)take(2ull * szC1);
    ushort* C1tL = (ushort*)take(2ull * szC1);
    ushort* C2tH = (ushort*)take(2ull * szC2);
    ushort* C2tL = (ushort*)take(2ull * szC2);
    ushort* C3tH = (ushort*)take(2ull * szC3);
    ushort* C3tL = (ushort*)take(2ull * szC3);
    float* out = (float*)d_out;

    const dim3 b256(256);

    // weight preprocessing (split + transpose)
    k_split_w<<<dim3((szW + 255) / 256), b256, 0, stream>>>(W1s, W1tH, W1tL, C_DIM, C_DIM, szW);
    k_split_w<<<dim3((szW + 255) / 256), b256, 0, stream>>>(W2s, W2tH, W2tL, C_DIM, C_DIM, szW);
    k_split_w<<<dim3((szW + 255) / 256), b256, 0, stream>>>(W3s, W3tH, W3tL, C_DIM, C_DIM, szW);
    k_split_w<<<dim3((szC1 + 255) / 256), b256, 0, stream>>>(cW1, C1tH, C1tL, C_DIM, C_DIM, szC1);
    k_split_w<<<dim3((szC2 + 255) / 256), b256, 0, stream>>>(cW2, C2tH, C2tL, C_DIM, 64, szC2);
    k_split_w<<<dim3((szC3 + 255) / 256), b256, 0, stream>>>(cW3, C3tH, C3tL, 64, C_DIM, szC3);

    // CSR build
    k_zero_i32<<<dim3((n + 255) / 256), b256, 0, stream>>>(cur, n);
    k_hist<<<dim3((E + 255) / 256), b256, 0, stream>>>(dst, E, cur);
    k_scan<<<1, 1024, 0, stream>>>(cur, off, n);
    k_copy_i32<<<dim3((n + 255) / 256), b256, 0, stream>>>(off, cur, n);
    k_scatter<<<dim3((E + 255) / 256), b256, 0, stream>>>(src, dst, E, cur, adj);

    const int gx = (n + 63) / 64;
    const dim3 gAgg((n + 3) / 4);

    const float* xp = x;
    for (int l = 0; l < NL; l++) {
        const size_t wo = (size_t)l * C_DIM * C_DIM;
        k_agg<<<gAgg, b256, 0, stream>>>(xp, off, adj, bufH, n);
        k_gemm_mfma<1><<<dim3(gx, 4), b256, 0, stream>>>(bufH, W1tH + wo, W1tL + wo, b1s + l * C_DIM, bufA, n, C_DIM, C_DIM);
        k_gemm_mfma<1><<<dim3(gx, 4), b256, 0, stream>>>(bufA, W2tH + wo, W2tL + wo, b2s + l * C_DIM, out,  n, C_DIM, C_DIM);
        k_gemm_mfma<0><<<dim3(gx, 4), b256, 0, stream>>>(out,  W3tH + wo, W3tL + wo, b3s + l * C_DIM, bufA, n, C_DIM, C_DIM);
        xp = bufA;
    }
    // final conv: C->C (relu), C->64 (relu), 64->C (linear)
    k_agg<<<gAgg, b256, 0, stream>>>(xp, off, adj, bufH, n);
    k_gemm_mfma<1><<<dim3(gx, 4), b256, 0, stream>>>(bufH, C1tH, C1tL, cb1, bufA, n, C_DIM, C_DIM);
    k_gemm_mfma<1><<<dim3(gx, 1), b256, 0, stream>>>(bufA, C2tH, C2tL, cb2, bufH, n, C_DIM, 64);
    k_gemm_mfma<0><<<dim3(gx, 4), b256, 0, stream>>>(bufH, C3tH, C3tL, cb3, out, n, 64, C_DIM);
}